// Round 3
// baseline (179.212 us; speedup 1.0000x reference)
//
#include <hip/hip_runtime.h>

// Problem constants
constexpr int IN_C  = 256;
constexpr int MID   = 32;
constexpr int OUT_C = 128;
constexpr int NR    = 512;
constexpr int NL    = 256;
constexpr int M     = 4;
constexpr long ROW_STRIDE = (long)(NR + NL) * OUT_C;   // 768*128 = 98304

// ---- workspace layout ----
// f32 region (float offsets)
constexpr long WS_PR4 = 0;                               // [4][512][32]   (rec proj, slice-major)
constexpr long WS_PL4 = WS_PR4 + 4L * NR * MID;          // [4][4][256][32] (lig proj [s][m][j][y])
constexpr long WS_F32_END = WS_PL4 + 4L * M * NL * MID;  // 196608 floats
// bf16 region (ushort offsets into ws)
constexpr long BF_LRR = 2 * WS_F32_END;                  // [512][32]  r_ri
constexpr long BF_LRL = BF_LRR + (long)NR * MID;         // [512][32]  r_li
constexpr long BF_LLR = BF_LRL + (long)NR * MID;         // [512][32]  r_lj
constexpr long BF_LLL = BF_LLR + (long)NR * MID;         // [256][128] l_li gathered [i][m*32+x]
constexpr long BF_TRR = BF_LLL + (long)NL * M * MID;     // [512][128][32]  T[j][o][k]
constexpr long BF_TRL = BF_TRR + (long)NR * OUT_C * MID; // [256][128][32]
constexpr long BF_TLR = BF_TRL + (long)NL * OUT_C * MID; // [256][128][32]
constexpr long BF_TLL = BF_TLR + (long)NL * OUT_C * MID; // [256][128][128]

typedef __bf16 bf16x8 __attribute__((ext_vector_type(8)));
typedef float  f32x4  __attribute__((ext_vector_type(4)));

__device__ inline unsigned short f2bf(float f) {
    unsigned int u = __float_as_uint(f);
    u = (u + 0x7fffu + ((u >> 16) & 1u)) >> 16;   // round-to-nearest-even
    return (unsigned short)u;
}

// ---------------------------------------------------------------------------
// K1: LayerNorm + projection. One block per row (512 rec + 1024 lig rows).
// f32 slices P4[s][row][x] for T-build inputs; bf16 L arrays for the MFMA epilogue.
// ---------------------------------------------------------------------------
__global__ __launch_bounds__(256) void ln_proj_kernel(
    const float* __restrict__ rec, const float* __restrict__ lig,
    const float* __restrict__ rg, const float* __restrict__ rb,
    const float* __restrict__ lg, const float* __restrict__ lb,
    const float* __restrict__ Wr, const float* __restrict__ br,
    const float* __restrict__ Wl, const float* __restrict__ bl,
    float* __restrict__ ws)
{
    int row = blockIdx.x;
    bool isRec = (row < NR);
    const float *X, *g, *bvec, *W, *bias;
    float* P4;
    long slice_stride;
    int prow;
    if (isRec) {
        X = rec + (long)row * IN_C; g = rg; bvec = rb; W = Wr; bias = br;
        P4 = ws + WS_PR4; slice_stride = (long)NR * MID; prow = row;
    } else {
        int rl_ = row - NR;                       // m*256 + j
        X = lig + (long)rl_ * IN_C; g = lg; bvec = lb; W = Wl; bias = bl;
        P4 = ws + WS_PL4; slice_stride = (long)M * NL * MID; prow = rl_;
    }

    __shared__ __align__(16) float xn[IN_C];
    __shared__ float red[8];
    __shared__ float musig[2];
    __shared__ float part[256];

    int tid = threadIdx.x;
    float x = X[tid];
    float s = x, s2 = x * x;
    #pragma unroll
    for (int off = 32; off > 0; off >>= 1) {
        s  += __shfl_down(s,  off, 64);
        s2 += __shfl_down(s2, off, 64);
    }
    int wid = tid >> 6;
    if ((tid & 63) == 0) { red[wid] = s; red[4 + wid] = s2; }
    __syncthreads();
    if (tid == 0) {
        float sum  = red[0] + red[1] + red[2] + red[3];
        float sum2 = red[4] + red[5] + red[6] + red[7];
        float mu  = sum * (1.f / IN_C);
        float var = sum2 * (1.f / IN_C) - mu * mu;
        musig[0] = mu;
        musig[1] = rsqrtf(var + 1e-5f);
    }
    __syncthreads();
    float mu = musig[0], rs = musig[1];
    xn[tid] = (x - mu) * rs * g[tid] + bvec[tid];
    __syncthreads();

    // projection: 128 outputs, 2 threads each (half dots)
    int c = tid & 127, h = tid >> 7;
    const float* wrow = W + (long)c * IN_C + h * 128;
    const float* xp   = xn + h * 128;
    float acc = 0.f;
    #pragma unroll
    for (int k = 0; k < 128; k += 4) {
        float4 w4 = *(const float4*)(wrow + k);
        float4 x4 = *(const float4*)(xp + k);
        acc += w4.x * x4.x + w4.y * x4.y + w4.z * x4.z + w4.w * x4.w;
    }
    part[tid] = acc;
    __syncthreads();
    if (tid < 128) {
        float val = part[tid] + part[tid + 128] + bias[tid];
        int slice = tid & 3, xi = tid >> 2;
        P4[(long)slice * slice_stride + (long)prow * MID + xi] = val;

        unsigned short hb = f2bf(val);
        unsigned short* wsb = (unsigned short*)ws;
        if (isRec) {
            if (slice == 0)      wsb[BF_LRR + (long)prow * 32 + xi] = hb;   // r_ri
            else if (slice == 2) wsb[BF_LRL + (long)prow * 32 + xi] = hb;   // r_li
            else if (slice == 3) wsb[BF_LLR + (long)prow * 32 + xi] = hb;   // r_lj
        } else {
            if (slice == 2)      // l_li -> L_ll[i][m*32+x]
                wsb[BF_LLL + (long)(prow & 255) * 128 + (prow >> 8) * 32 + xi] = hb;
        }
    }
}

// ---------------------------------------------------------------------------
// K3: T[j][o][k] (bf16) = scale * sum_y W[o,x,y] * V[j,y]   (k = x, or m*32+x for ll)
// Means over m for rl/lr are computed inline while staging V.
// Block = (quadrant, j-tile of 16, column chunk of 1024 (o,x) pairs). 512 blocks.
// Thread handles two adjacent x for one o -> packed 4-byte coalesced bf16 writes.
// ---------------------------------------------------------------------------
__global__ __launch_bounds__(256) void build_t_kernel(
    const float* __restrict__ Wrr, const float* __restrict__ Wrl,
    const float* __restrict__ Wlr, const float* __restrict__ Wll,
    float* __restrict__ ws)
{
    unsigned short* wsb = (unsigned short*)ws;
    const float* V4 = ws + WS_PL4;   // [s][m][j][y]
    int bid = blockIdx.x;
    const float* W;
    unsigned short* T;
    float scale = 1.f;
    int mode, jt, cc, mm = 0, K;
    if (bid < 128)      { mode = 0; W = Wrr; T = wsb + BF_TRR; int r = bid;       jt = r >> 2; cc = r & 3; K = 32; }
    else if (bid < 192) { mode = 1; W = Wrl; T = wsb + BF_TRL; int r = bid - 128; jt = r >> 2; cc = r & 3; K = 32; }
    else if (bid < 256) { mode = 2; W = Wlr; T = wsb + BF_TLR; int r = bid - 192; jt = r >> 2; cc = r & 3; K = 32; }
    else                { mode = 3; W = Wll; T = wsb + BF_TLL; int r = bid - 256; mm = r >> 6; r &= 63;
                          jt = r >> 2; cc = r & 3; K = 128; scale = 0.25f; }
    int j0 = jt * 16;

    __shared__ __align__(16) float v[16][32];
    int tid = threadIdx.x;
    for (int f = tid; f < 512; f += 256) {
        int jl = f >> 5, y = f & 31;
        float val;
        if (mode == 0) {
            val = ws[WS_PR4 + 1L * NR * MID + (long)(j0 + jl) * MID + y];        // r_rj
        } else if (mode == 3) {
            val = V4[3L * M * NL * MID + (long)mm * NL * MID + (long)(j0 + jl) * MID + y]; // l_lj[m]
        } else {
            int sl = (mode == 1) ? 1 : 0;                                        // l_rj / l_ri
            const float* p = V4 + (long)sl * M * NL * MID + (long)(j0 + jl) * MID + y;
            val = 0.25f * (p[0] + p[NL * MID] + p[2L * NL * MID] + p[3L * NL * MID]);
        }
        v[jl][y] = val;
    }
    __syncthreads();

    int koff = (mode == 3) ? mm * 32 : 0;
    long jstride = (long)K * 128;
    #pragma unroll
    for (int pp = 0; pp < 2; ++pp) {
        int cpair = cc * 1024 + pp * 512 + tid * 2;  // c = o*32 + x, x even
        int o = cpair >> 5, x = cpair & 31;
        float wa[32], wb[32];
        const float4* wp = (const float4*)(W + (long)o * 1024 + x * 32);
        #pragma unroll
        for (int t4 = 0; t4 < 8; ++t4) {
            ((float4*)wa)[t4] = wp[t4];
            ((float4*)wb)[t4] = wp[t4 + 8];
        }
        long obase = (long)o * K + koff + x;
        for (int jl = 0; jl < 16; ++jl) {
            float accA = 0.f, accB = 0.f;
            #pragma unroll
            for (int y4 = 0; y4 < 8; ++y4) {
                float4 vv = *(const float4*)&v[jl][y4 * 4];
                accA += wa[y4*4+0]*vv.x + wa[y4*4+1]*vv.y + wa[y4*4+2]*vv.z + wa[y4*4+3]*vv.w;
                accB += wb[y4*4+0]*vv.x + wb[y4*4+1]*vv.y + wb[y4*4+2]*vv.z + wb[y4*4+3]*vv.w;
            }
            unsigned int pk = (unsigned int)f2bf(accA * scale)
                            | ((unsigned int)f2bf(accB * scale) << 16);
            *(unsigned int*)(T + (long)(j0 + jl) * jstride + obase) = pk;
        }
    }
}

// ---------------------------------------------------------------------------
// K4: MFMA epilogue. out(i,j,o) = bias[o] + sum_k L[i,k]*T[j,o,k]   (bf16 in, f32 out)
// OPERAND-SWAPPED: A = T[j] (rows = o), B = L (cols = i)  =>  D reg axis = o axis
// => per-lane float4 nontemporal stores along the contiguous o dimension.
// Block = (quadrant, it, j), it-major ordering: each XCD sweeps j contiguously.
// ---------------------------------------------------------------------------
__global__ __launch_bounds__(256) void epilogue_kernel(
    const float* __restrict__ ws, float* __restrict__ out,
    const float* __restrict__ brr, const float* __restrict__ brl,
    const float* __restrict__ blr, const float* __restrict__ bll)
{
    const unsigned short* wsb = (const unsigned short*)ws;
    int bid = blockIdx.x;
    int wk = (bid & 7) * 576 + (bid >> 3);     // 4608 = 8 * 576, bijective XCD swizzle

    const unsigned short *L, *T;
    const float* bias;
    float* ob;
    long istr, jstr;
    int K, j, it;
    if (wk < 2048) {            // rr: rows i (rec), cols j (rec)
        it = wk >> 9; j = wk & 511; K = 32;
        L = wsb + BF_LRR; T = wsb + BF_TRR + (long)j * 4096; bias = brr;
        ob = out; jstr = 128; istr = ROW_STRIDE;
    } else if (wk < 3072) {     // rl: rows i (rec), cols NR+j (lig)
        int w = wk - 2048; it = w >> 8; j = w & 255; K = 32;
        L = wsb + BF_LRL; T = wsb + BF_TRL + (long)j * 4096; bias = brl;
        ob = out + (long)NR * OUT_C; jstr = 128; istr = ROW_STRIDE;
    } else if (wk < 4096) {     // lr: rows NR+j (lig), cols i (rec)
        int w = wk - 3072; it = w >> 8; j = w & 255; K = 32;
        L = wsb + BF_LLR; T = wsb + BF_TLR + (long)j * 4096; bias = blr;
        ob = out + (long)NR * ROW_STRIDE; jstr = ROW_STRIDE; istr = 128;
    } else {                    // ll: rows NR+i, cols NR+j
        int w = wk - 4096; it = w >> 8; j = w & 255; K = 128;
        L = wsb + BF_LLL; T = wsb + BF_TLL + (long)j * 16384; bias = bll;
        ob = out + (long)NR * ROW_STRIDE + (long)NR * OUT_C; jstr = 128; istr = ROW_STRIDE;
    }

    int tid = threadIdx.x;
    int wv = tid >> 6, l = tid & 63;
    int lrow = l & 15, lk = l >> 4;
    int i0w = it * 128 + wv * 32;

    // acc[fi][of]: D tile rows = o (reg axis), cols = i. Init with bias (o-dependent).
    f32x4 acc[2][8];
    #pragma unroll
    for (int of = 0; of < 8; ++of) {
        f32x4 b4 = *(const f32x4*)(bias + of * 16 + lk * 4);
        acc[0][of] = b4; acc[1][of] = b4;
    }

    int nk = K >> 5;
    for (int ks = 0; ks < nk; ++ks) {
        int kb = ks * 32 + lk * 8;
        bf16x8 b0 = *(const bf16x8*)(L + (long)(i0w + lrow) * K + kb);
        bf16x8 b1 = *(const bf16x8*)(L + (long)(i0w + 16 + lrow) * K + kb);
        #pragma unroll
        for (int of = 0; of < 8; ++of) {
            bf16x8 a = *(const bf16x8*)(T + (long)(of * 16 + lrow) * K + kb);
            acc[0][of] = __builtin_amdgcn_mfma_f32_16x16x32_bf16(a, b0, acc[0][of], 0, 0, 0);
            acc[1][of] = __builtin_amdgcn_mfma_f32_16x16x32_bf16(a, b1, acc[1][of], 0, 0, 0);
        }
    }

    // D: col = l&15 -> i_local, row = lk*4 + r -> o_local. float4 along o.
    float* obase = ob + (long)j * jstr + (long)lk * 4;
    #pragma unroll
    for (int fi = 0; fi < 2; ++fi) {
        long ibase = (long)(i0w + fi * 16 + lrow) * istr;
        #pragma unroll
        for (int of = 0; of < 8; ++of) {
            __builtin_nontemporal_store(acc[fi][of],
                (f32x4*)(obase + ibase + of * 16));
        }
    }
}

extern "C" void kernel_launch(void* const* d_in, const int* in_sizes, int n_in,
                              void* d_out, int out_size, void* d_ws, size_t ws_size,
                              hipStream_t stream)
{
    (void)in_sizes; (void)n_in; (void)out_size; (void)ws_size;
    const float* rec = (const float*)d_in[0];
    const float* lig = (const float*)d_in[1];
    // d_in[2] = pw_rep: shape-only, never read (all 4 quadrants are overwritten)
    const float* rg  = (const float*)d_in[3];
    const float* rb  = (const float*)d_in[4];
    const float* lg  = (const float*)d_in[5];
    const float* lb  = (const float*)d_in[6];
    const float* Wr  = (const float*)d_in[7];
    const float* br  = (const float*)d_in[8];
    const float* Wl  = (const float*)d_in[9];
    const float* bl  = (const float*)d_in[10];
    const float* Wrr = (const float*)d_in[11];
    const float* brr = (const float*)d_in[12];
    const float* Wrl = (const float*)d_in[13];
    const float* brl = (const float*)d_in[14];
    const float* Wlr = (const float*)d_in[15];
    const float* blr = (const float*)d_in[16];
    const float* Wll = (const float*)d_in[17];
    const float* bll = (const float*)d_in[18];
    float* out = (float*)d_out;
    float* ws  = (float*)d_ws;

    hipLaunchKernelGGL(ln_proj_kernel, dim3(NR + M * NL), dim3(256), 0, stream,
                       rec, lig, rg, rb, lg, lb, Wr, br, Wl, bl, ws);
    hipLaunchKernelGGL(build_t_kernel, dim3(512), dim3(256), 0, stream,
                       Wrr, Wrl, Wlr, Wll, ws);
    hipLaunchKernelGGL(epilogue_kernel, dim3(4608), dim3(256), 0, stream,
                       ws, out, brr, brl, blr, bll);
}

// Round 4
// 120.405 us; speedup vs baseline: 1.4884x; 1.4884x over previous
//
#include <hip/hip_runtime.h>

// Problem constants
constexpr int IN_C  = 256;
constexpr int MID   = 32;
constexpr int OUT_C = 128;
constexpr int NR    = 512;
constexpr int NL    = 256;
constexpr int M     = 4;
constexpr long ROW_STRIDE = (long)(NR + NL) * OUT_C;   // 768*128 = 98304

// ---- workspace layout ----
// f32 region (float offsets)
constexpr long WS_PR4 = 0;                               // [4][512][32]   (rec proj, slice-major)
constexpr long WS_PL4 = WS_PR4 + 4L * NR * MID;          // [4][4][256][32] (lig proj [s][m][j][y])
constexpr long WS_F32_END = WS_PL4 + 4L * M * NL * MID;  // 196608 floats
// bf16 region (ushort offsets into ws)
constexpr long BF_LRR = 2 * WS_F32_END;                  // [512][32]  r_ri
constexpr long BF_LRL = BF_LRR + (long)NR * MID;         // [512][32]  r_li
constexpr long BF_LLR = BF_LRL + (long)NR * MID;         // [512][32]  r_lj
constexpr long BF_LLL = BF_LLR + (long)NR * MID;         // [256][128] l_li gathered [i][m*32+x]
constexpr long BF_TRR = BF_LLL + (long)NL * M * MID;     // [512][128][32]  T[j][o][k]
constexpr long BF_TRL = BF_TRR + (long)NR * OUT_C * MID; // [256][128][32]
constexpr long BF_TLR = BF_TRL + (long)NL * OUT_C * MID; // [256][128][32]
constexpr long BF_TLL = BF_TLR + (long)NL * OUT_C * MID; // [256][128][128]

typedef __bf16 bf16x8 __attribute__((ext_vector_type(8)));
typedef float  f32x4  __attribute__((ext_vector_type(4)));

__device__ inline unsigned short f2bf(float f) {
    unsigned int u = __float_as_uint(f);
    u = (u + 0x7fffu + ((u >> 16) & 1u)) >> 16;   // round-to-nearest-even
    return (unsigned short)u;
}

// ---------------------------------------------------------------------------
// K1: LayerNorm + projection. One block per row (512 rec + 1024 lig rows).
// f32 slices P4[s][row][x] for T-build inputs; bf16 L arrays for the MFMA epilogue.
// ---------------------------------------------------------------------------
__global__ __launch_bounds__(256) void ln_proj_kernel(
    const float* __restrict__ rec, const float* __restrict__ lig,
    const float* __restrict__ rg, const float* __restrict__ rb,
    const float* __restrict__ lg, const float* __restrict__ lb,
    const float* __restrict__ Wr, const float* __restrict__ br,
    const float* __restrict__ Wl, const float* __restrict__ bl,
    float* __restrict__ ws)
{
    int row = blockIdx.x;
    bool isRec = (row < NR);
    const float *X, *g, *bvec, *W, *bias;
    float* P4;
    long slice_stride;
    int prow;
    if (isRec) {
        X = rec + (long)row * IN_C; g = rg; bvec = rb; W = Wr; bias = br;
        P4 = ws + WS_PR4; slice_stride = (long)NR * MID; prow = row;
    } else {
        int rl_ = row - NR;                       // m*256 + j
        X = lig + (long)rl_ * IN_C; g = lg; bvec = lb; W = Wl; bias = bl;
        P4 = ws + WS_PL4; slice_stride = (long)M * NL * MID; prow = rl_;
    }

    __shared__ __align__(16) float xn[IN_C];
    __shared__ float red[8];
    __shared__ float musig[2];
    __shared__ float part[256];

    int tid = threadIdx.x;
    float x = X[tid];
    float s = x, s2 = x * x;
    #pragma unroll
    for (int off = 32; off > 0; off >>= 1) {
        s  += __shfl_down(s,  off, 64);
        s2 += __shfl_down(s2, off, 64);
    }
    int wid = tid >> 6;
    if ((tid & 63) == 0) { red[wid] = s; red[4 + wid] = s2; }
    __syncthreads();
    if (tid == 0) {
        float sum  = red[0] + red[1] + red[2] + red[3];
        float sum2 = red[4] + red[5] + red[6] + red[7];
        float mu  = sum * (1.f / IN_C);
        float var = sum2 * (1.f / IN_C) - mu * mu;
        musig[0] = mu;
        musig[1] = rsqrtf(var + 1e-5f);
    }
    __syncthreads();
    float mu = musig[0], rs = musig[1];
    xn[tid] = (x - mu) * rs * g[tid] + bvec[tid];
    __syncthreads();

    // projection: 128 outputs, 2 threads each (half dots)
    int c = tid & 127, h = tid >> 7;
    const float* wrow = W + (long)c * IN_C + h * 128;
    const float* xp   = xn + h * 128;
    float acc = 0.f;
    #pragma unroll
    for (int k = 0; k < 128; k += 4) {
        float4 w4 = *(const float4*)(wrow + k);
        float4 x4 = *(const float4*)(xp + k);
        acc += w4.x * x4.x + w4.y * x4.y + w4.z * x4.z + w4.w * x4.w;
    }
    part[tid] = acc;
    __syncthreads();
    if (tid < 128) {
        float val = part[tid] + part[tid + 128] + bias[tid];
        int slice = tid & 3, xi = tid >> 2;
        P4[(long)slice * slice_stride + (long)prow * MID + xi] = val;

        unsigned short hb = f2bf(val);
        unsigned short* wsb = (unsigned short*)ws;
        if (isRec) {
            if (slice == 0)      wsb[BF_LRR + (long)prow * 32 + xi] = hb;   // r_ri
            else if (slice == 2) wsb[BF_LRL + (long)prow * 32 + xi] = hb;   // r_li
            else if (slice == 3) wsb[BF_LLR + (long)prow * 32 + xi] = hb;   // r_lj
        } else {
            if (slice == 2)      // l_li -> L_ll[i][m*32+x]
                wsb[BF_LLL + (long)(prow & 255) * 128 + (prow >> 8) * 32 + xi] = hb;
        }
    }
}

// ---------------------------------------------------------------------------
// K3: T[j][o][k] (bf16) = scale * sum_y W[o,x,y] * V[j,y]   (k = x, or m*32+x for ll)
// Means over m for rl/lr are computed inline while staging V.
// Block = (quadrant, j-tile of 32, column chunk of 1024 (o,x) pairs). 256 blocks.
// Thread handles two adjacent x for one o -> packed 4-byte coalesced bf16 writes.
// ---------------------------------------------------------------------------
__global__ __launch_bounds__(256) void build_t_kernel(
    const float* __restrict__ Wrr, const float* __restrict__ Wrl,
    const float* __restrict__ Wlr, const float* __restrict__ Wll,
    float* __restrict__ ws)
{
    unsigned short* wsb = (unsigned short*)ws;
    const float* V4 = ws + WS_PL4;   // [s][m][j][y]
    int bid = blockIdx.x;
    const float* W;
    unsigned short* T;
    float scale = 1.f;
    int mode, jt, cc, mm = 0, K;
    if (bid < 64)       { mode = 0; W = Wrr; T = wsb + BF_TRR; int r = bid;       jt = r >> 2; cc = r & 3; K = 32; }
    else if (bid < 96)  { mode = 1; W = Wrl; T = wsb + BF_TRL; int r = bid - 64;  jt = r >> 2; cc = r & 3; K = 32; }
    else if (bid < 128) { mode = 2; W = Wlr; T = wsb + BF_TLR; int r = bid - 96;  jt = r >> 2; cc = r & 3; K = 32; }
    else                { mode = 3; W = Wll; T = wsb + BF_TLL; int r = bid - 128; mm = r >> 5; r &= 31;
                          jt = r >> 2; cc = r & 3; K = 128; scale = 0.25f; }
    int j0 = jt * 32;

    __shared__ __align__(16) float v[32][32];
    int tid = threadIdx.x;
    for (int f = tid; f < 1024; f += 256) {
        int jl = f >> 5, y = f & 31;
        float val;
        if (mode == 0) {
            val = ws[WS_PR4 + 1L * NR * MID + (long)(j0 + jl) * MID + y];        // r_rj
        } else if (mode == 3) {
            val = V4[3L * M * NL * MID + (long)mm * NL * MID + (long)(j0 + jl) * MID + y]; // l_lj[m]
        } else {
            int sl = (mode == 1) ? 1 : 0;                                        // l_rj / l_ri
            const float* p = V4 + (long)sl * M * NL * MID + (long)(j0 + jl) * MID + y;
            val = 0.25f * (p[0] + p[NL * MID] + p[2L * NL * MID] + p[3L * NL * MID]);
        }
        v[jl][y] = val;
    }
    __syncthreads();

    int koff = (mode == 3) ? mm * 32 : 0;
    long jstride = (long)K * 128;
    #pragma unroll
    for (int pp = 0; pp < 2; ++pp) {
        int cpair = cc * 1024 + pp * 512 + tid * 2;  // c = o*32 + x, x even
        int o = cpair >> 5, x = cpair & 31;
        float wa[32], wb[32];
        const float4* wp = (const float4*)(W + (long)o * 1024 + x * 32);
        #pragma unroll
        for (int t4 = 0; t4 < 8; ++t4) {
            ((float4*)wa)[t4] = wp[t4];
            ((float4*)wb)[t4] = wp[t4 + 8];
        }
        long obase = (long)o * K + koff + x;
        for (int jl = 0; jl < 32; ++jl) {
            float accA = 0.f, accB = 0.f;
            #pragma unroll
            for (int y4 = 0; y4 < 8; ++y4) {
                float4 vv = *(const float4*)&v[jl][y4 * 4];
                accA += wa[y4*4+0]*vv.x + wa[y4*4+1]*vv.y + wa[y4*4+2]*vv.z + wa[y4*4+3]*vv.w;
                accB += wb[y4*4+0]*vv.x + wb[y4*4+1]*vv.y + wb[y4*4+2]*vv.z + wb[y4*4+3]*vv.w;
            }
            unsigned int pk = (unsigned int)f2bf(accA * scale)
                            | ((unsigned int)f2bf(accB * scale) << 16);
            *(unsigned int*)(T + (long)(j0 + jl) * jstride + obase) = pk;
        }
    }
}

// ---------------------------------------------------------------------------
// K4: MFMA epilogue. out(i,j,o) = bias[o] + sum_k L[i,k]*T[j,o,k]   (bf16 in, f32 out)
// Operand-swapped: A = T[j] (rows = o), B = L (cols = i) => D reg axis = o axis
// => per-lane float4 CACHED stores along contiguous o (L2 merges 64B segments).
// Balanced XCD slicing: each XCD gets 256 rr + 128 rl + 128 lr + 64 ll blocks
// (ll is 4x work: K=128) with a j-adjacent window -> equal work per XCD,
// T[j] read once per XCD, concurrent blocks write adjacent 512B output chunks.
// ---------------------------------------------------------------------------
__global__ __launch_bounds__(256) void epilogue_kernel(
    const float* __restrict__ ws, float* __restrict__ out,
    const float* __restrict__ brr, const float* __restrict__ brl,
    const float* __restrict__ blr, const float* __restrict__ bll)
{
    const unsigned short* wsb = (const unsigned short*)ws;
    int bid = blockIdx.x;
    int x = bid & 7;      // XCD (dispatch round-robin heuristic; perf-only)
    int r = bid >> 3;     // 0..575 within XCD

    const unsigned short *L, *T;
    const float* bias;
    float* ob;
    long istr, jstr;
    int K, j, it;
    if (r < 256) {              // rr: rows i (rec), cols j (rec); it 0..3, j window 64
        it = r >> 6; j = x * 64 + (r & 63); K = 32;
        L = wsb + BF_LRR; T = wsb + BF_TRR + (long)j * 4096; bias = brr;
        ob = out; jstr = 128; istr = ROW_STRIDE;
    } else if (r < 384) {       // rl: rows i (rec), cols NR+j (lig); it 0..3, j window 32
        int w = r - 256; it = w >> 5; j = x * 32 + (w & 31); K = 32;
        L = wsb + BF_LRL; T = wsb + BF_TRL + (long)j * 4096; bias = brl;
        ob = out + (long)NR * OUT_C; jstr = 128; istr = ROW_STRIDE;
    } else if (r < 512) {       // lr: rows NR+j (lig), cols i (rec); it 0..3, j window 32
        int w = r - 384; it = w >> 5; j = x * 32 + (w & 31); K = 32;
        L = wsb + BF_LLR; T = wsb + BF_TLR + (long)j * 4096; bias = blr;
        ob = out + (long)NR * ROW_STRIDE; jstr = ROW_STRIDE; istr = 128;
    } else {                    // ll: rows NR+i, cols NR+j; it 0..1, j window 32, K=128
        int w = r - 512; it = w >> 5; j = x * 32 + (w & 31); K = 128;
        L = wsb + BF_LLL; T = wsb + BF_TLL + (long)j * 16384; bias = bll;
        ob = out + (long)NR * ROW_STRIDE + (long)NR * OUT_C; jstr = 128; istr = ROW_STRIDE;
    }

    int tid = threadIdx.x;
    int wv = tid >> 6, l = tid & 63;
    int lrow = l & 15, lk = l >> 4;
    int i0w = it * 128 + wv * 32;

    // acc[fi][of]: D tile rows = o (reg axis), cols = i (lanes). Bias folded in.
    f32x4 acc[2][8];
    #pragma unroll
    for (int of = 0; of < 8; ++of) {
        f32x4 b4 = *(const f32x4*)(bias + of * 16 + lk * 4);
        acc[0][of] = b4; acc[1][of] = b4;
    }

    int nk = K >> 5;
    for (int ks = 0; ks < nk; ++ks) {
        int kb = ks * 32 + lk * 8;
        bf16x8 b0 = *(const bf16x8*)(L + (long)(i0w + lrow) * K + kb);
        bf16x8 b1 = *(const bf16x8*)(L + (long)(i0w + 16 + lrow) * K + kb);
        #pragma unroll
        for (int of = 0; of < 8; ++of) {
            bf16x8 a = *(const bf16x8*)(T + (long)(of * 16 + lrow) * K + kb);
            acc[0][of] = __builtin_amdgcn_mfma_f32_16x16x32_bf16(a, b0, acc[0][of], 0, 0, 0);
            acc[1][of] = __builtin_amdgcn_mfma_f32_16x16x32_bf16(a, b1, acc[1][of], 0, 0, 0);
        }
    }

    // D: col = l&15 -> i_local, row = lk*4 + r -> o_local. float4 along o, cached.
    float* obase = ob + (long)j * jstr + (long)lk * 4;
    #pragma unroll
    for (int fi = 0; fi < 2; ++fi) {
        long ibase = (long)(i0w + fi * 16 + lrow) * istr;
        #pragma unroll
        for (int of = 0; of < 8; ++of) {
            *(f32x4*)(obase + ibase + of * 16) = acc[fi][of];
        }
    }
}

extern "C" void kernel_launch(void* const* d_in, const int* in_sizes, int n_in,
                              void* d_out, int out_size, void* d_ws, size_t ws_size,
                              hipStream_t stream)
{
    (void)in_sizes; (void)n_in; (void)out_size; (void)ws_size;
    const float* rec = (const float*)d_in[0];
    const float* lig = (const float*)d_in[1];
    // d_in[2] = pw_rep: shape-only, never read (all 4 quadrants are overwritten)
    const float* rg  = (const float*)d_in[3];
    const float* rb  = (const float*)d_in[4];
    const float* lg  = (const float*)d_in[5];
    const float* lb  = (const float*)d_in[6];
    const float* Wr  = (const float*)d_in[7];
    const float* br  = (const float*)d_in[8];
    const float* Wl  = (const float*)d_in[9];
    const float* bl  = (const float*)d_in[10];
    const float* Wrr = (const float*)d_in[11];
    const float* brr = (const float*)d_in[12];
    const float* Wrl = (const float*)d_in[13];
    const float* brl = (const float*)d_in[14];
    const float* Wlr = (const float*)d_in[15];
    const float* blr = (const float*)d_in[16];
    const float* Wll = (const float*)d_in[17];
    const float* bll = (const float*)d_in[18];
    float* out = (float*)d_out;
    float* ws  = (float*)d_ws;

    hipLaunchKernelGGL(ln_proj_kernel, dim3(NR + M * NL), dim3(256), 0, stream,
                       rec, lig, rg, rb, lg, lb, Wr, br, Wl, bl, ws);
    hipLaunchKernelGGL(build_t_kernel, dim3(256), dim3(256), 0, stream,
                       Wrr, Wrl, Wlr, Wll, ws);
    hipLaunchKernelGGL(epilogue_kernel, dim3(4608), dim3(256), 0, stream,
                       ws, out, brr, brl, blr, bll);
}